// Round 7
// baseline (1634.668 us; speedup 1.0000x reference)
//
#include <hip/hip_runtime.h>

#define NPTS 2048
#define NB   16

// eps = 0.01, log-domain Sinkhorn in base-2.
constexpr float K_R          = 144.26950408889634f;    // log2(e)/eps
constexpr float K_TWO_R      = 288.53900817779268f;    // 2*K_R
constexpr float K_EPS_LN2    = 0.0069314718055994531f; // eps*ln2
constexpr float K_EPS_LOGMRG = -0.076246189861593985f; // eps*ln(1/2048)

__device__ __forceinline__ float fexp2(float x) { return __builtin_amdgcn_exp2f(x); }
__device__ __forceinline__ float flog2(float x) { return __builtin_amdgcn_logf(x); }

// ---------------------------------------------------------------- prep ------
__global__ __launch_bounds__(256) void prep_kernel(
    const float* __restrict__ x, const float* __restrict__ y,
    float4* __restrict__ px, float4* __restrict__ py, float* __restrict__ g)
{
    int idx = blockIdx.x * 256 + threadIdx.x;
    if (idx >= NB * NPTS) return;
    float x0 = x[idx*3+0], x1 = x[idx*3+1], x2 = x[idx*3+2];
    px[idx] = make_float4(x0, x1, x2, fmaf(x0,x0, fmaf(x1,x1, x2*x2)));
    float y0 = y[idx*3+0], y1 = y[idx*3+1], y2 = y[idx*3+2];
    py[idx] = make_float4(y0, y1, y2, fmaf(y0,y0, fmaf(y1,y1, y2*y2)));
    g[idx] = 0.0f;
}

// ------------------------------------------------------------ half step -----
// dual_out[i] = eps*log(1/N) - eps*ln2 * log2( sum_j 2^{(dual_j - C_ij)*R} )
// 1024-thread wg (1 per CU, 16 waves), 16 wgs/batch -> 128 rows/wg, 8/wave.
// Panel staged to LDS once per CU. Inner loop: depth-4 float4 pipeline.
__global__ __launch_bounds__(1024, 4) void half_step(
    const float4* __restrict__ pcol, const float* __restrict__ dual_in,
    const float4* __restrict__ prow, float* __restrict__ dual_out)
{
    __shared__ float4 ld[NPTS];   // (y*2R, (dual-|y|^2)*R), linear

    const int b     = blockIdx.x >> 4;
    const int chunk = blockIdx.x & 15;
    const int tid   = threadIdx.x;

    const float4* pc = pcol    + b * NPTS;
    const float*  di = dual_in + b * NPTS;

    #pragma unroll
    for (int i2 = 0; i2 < 2; ++i2) {
        int k = i2 * 1024 + tid;
        float4 p = pc[k];
        ld[k] = make_float4(p.x * K_TWO_R, p.y * K_TWO_R, p.z * K_TWO_R,
                            (di[k] - p.w) * K_R);
    }

    const int lane = tid & 63;
    const int wid  = tid >> 6;            // 0..15
    const int row0 = chunk * 128 + wid * 8;

    float rx[8], ry[8], rz[8], u0[8];
    #pragma unroll
    for (int r = 0; r < 8; ++r) {
        float4 xi = prow[b * NPTS + row0 + r];
        rx[r] = xi.x; ry[r] = xi.y; rz[r] = xi.z; u0[r] = -xi.w * K_R;
    }

    __syncthreads();

    // depth-4 software pipeline over 32 chunk-reads
    float4 p0 = ld[lane], p1 = ld[64 + lane], p2 = ld[128 + lane], p3 = ld[192 + lane];
    float acc[8] = {0.f,0.f,0.f,0.f,0.f,0.f,0.f,0.f};
    for (int c = 0; c < 32; c += 2) {
        float4 n0 = ld[((c + 4) & 31) * 64 + lane];
        float4 n1 = ld[((c + 5) & 31) * 64 + lane];
        #pragma unroll
        for (int r = 0; r < 8; ++r) {
            float w = fmaf(p0.x, rx[r], fmaf(p0.y, ry[r], fmaf(p0.z, rz[r], p0.w + u0[r])));
            acc[r] += fexp2(w);
        }
        #pragma unroll
        for (int r = 0; r < 8; ++r) {
            float w = fmaf(p1.x, rx[r], fmaf(p1.y, ry[r], fmaf(p1.z, rz[r], p1.w + u0[r])));
            acc[r] += fexp2(w);
        }
        p0 = p2; p1 = p3; p2 = n0; p3 = n1;
    }

    #pragma unroll
    for (int r = 0; r < 8; ++r) {
        #pragma unroll
        for (int off = 1; off < 64; off <<= 1)
            acc[r] += __shfl_xor(acc[r], off, 64);
    }
    if (lane < 8) {
        float s = acc[0];
        #pragma unroll
        for (int r = 1; r < 8; ++r) s = (lane == r) ? acc[r] : s;
        dual_out[b * NPTS + row0 + lane] =
            K_EPS_LOGMRG - K_EPS_LN2 * flog2(s);
    }
}

// ---------------------------------------------------------------- emd -------
// out[b] = sum_ij 2^{(f_i + g_j - C_ij)*R} * C_ij, same structure.
__global__ __launch_bounds__(1024, 4) void emd_kernel(
    const float4* __restrict__ px, const float4* __restrict__ py,
    const float* __restrict__ f, const float* __restrict__ g,
    float* __restrict__ out)
{
    __shared__ float4 ld[NPTS];   // (y raw, |y|^2)
    __shared__ float  hh[NPTS];   // (g-|y|^2)*R
    __shared__ float  wsum[16];

    const int b     = blockIdx.x >> 4;
    const int chunk = blockIdx.x & 15;
    const int tid   = threadIdx.x;

    #pragma unroll
    for (int i2 = 0; i2 < 2; ++i2) {
        int k = i2 * 1024 + tid;
        float4 p = py[b * NPTS + k];
        ld[k] = p;
        hh[k] = (g[b * NPTS + k] - p.w) * K_R;
    }

    const int lane = tid & 63;
    const int wid  = tid >> 6;
    const int row0 = chunk * 128 + wid * 8;

    float rx[8], ry[8], rz[8], rw[8], u2[8];
    #pragma unroll
    for (int r = 0; r < 8; ++r) {
        float4 xi = px[b * NPTS + row0 + r];
        rx[r] = xi.x; ry[r] = xi.y; rz[r] = xi.z; rw[r] = xi.w;
        u2[r] = (f[b * NPTS + row0 + r] - xi.w) * K_R;
    }

    __syncthreads();

    float4 p0 = ld[lane], p1 = ld[64 + lane];
    float  h0 = hh[lane], h1 = hh[64 + lane];
    float acc = 0.f;
    for (int c = 0; c < 32; c += 2) {
        float4 n0 = ld[((c + 2) & 31) * 64 + lane];
        float4 n1 = ld[((c + 3) & 31) * 64 + lane];
        float  m0 = hh[((c + 2) & 31) * 64 + lane];
        float  m1 = hh[((c + 3) & 31) * 64 + lane];
        #pragma unroll
        for (int r = 0; r < 8; ++r) {
            float d = fmaf(p0.x, rx[r], fmaf(p0.y, ry[r], p0.z * rz[r]));
            float C = fmaf(-2.0f, d, rw[r] + p0.w);
            float t = fmaf(K_TWO_R, d, u2[r] + h0);
            acc = fmaf(fexp2(t), C, acc);
        }
        #pragma unroll
        for (int r = 0; r < 8; ++r) {
            float d = fmaf(p1.x, rx[r], fmaf(p1.y, ry[r], p1.z * rz[r]));
            float C = fmaf(-2.0f, d, rw[r] + p1.w);
            float t = fmaf(K_TWO_R, d, u2[r] + h1);
            acc = fmaf(fexp2(t), C, acc);
        }
        p0 = n0; p1 = n1; h0 = m0; h1 = m1;
    }

    #pragma unroll
    for (int off = 1; off < 64; off <<= 1) acc += __shfl_xor(acc, off, 64);
    if (lane == 0) wsum[wid] = acc;
    __syncthreads();
    if (tid == 0) {
        float s = 0.f;
        #pragma unroll
        for (int i2 = 0; i2 < 16; ++i2) s += wsum[i2];
        atomicAdd(&out[b], s);
    }
}

// -------------------------------------------------------------- launch ------
extern "C" void kernel_launch(void* const* d_in, const int* in_sizes, int n_in,
                              void* d_out, int out_size, void* d_ws, size_t ws_size,
                              hipStream_t stream)
{
    const float* x = (const float*)d_in[0];
    const float* y = (const float*)d_in[1];
    float* out = (float*)d_out;

    char* ws = (char*)d_ws;
    float4* px = (float4*)(ws);
    float4* py = (float4*)(ws + (size_t)NB * NPTS * 16);
    float*  f  = (float*) (ws + (size_t)NB * NPTS * 32);
    float*  g  = (float*) (ws + (size_t)NB * NPTS * 32 + (size_t)NB * NPTS * 4);

    hipMemsetAsync(d_out, 0, (size_t)out_size * sizeof(float), stream);

    prep_kernel<<<(NB * NPTS + 255) / 256, 256, 0, stream>>>(x, y, px, py, g);

    for (int it = 0; it < 50; ++it) {
        half_step<<<256, 1024, 0, stream>>>(py, g, px, f);  // f-update
        half_step<<<256, 1024, 0, stream>>>(px, f, py, g);  // g-update
    }

    emd_kernel<<<256, 1024, 0, stream>>>(px, py, f, g, out);
}